// Round 15
// baseline (115.439 us; speedup 1.0000x reference)
//
#include <hip/hip_runtime.h>
#include <math.h>

#define NB 16
#define NS 48
#define NL 64
#define NQ 32
#define NE 300
#define NF 256
#define KP 320            // padded K for embeddings (bf16)
#define QROWS 36          // qe rows per b (32 + zero pad for taps)

typedef __attribute__((ext_vector_type(8))) short short8;
typedef __attribute__((ext_vector_type(4))) float f32x4;

#define MFMA(a,b,c) __builtin_amdgcn_mfma_f32_16x16x32_bf16((a),(b),(c),0,0,0)

__device__ __forceinline__ unsigned short f2bf(float f) {
    unsigned u = __float_as_uint(f);
    u += 0x7fff + ((u >> 16) & 1);           // RNE
    return (unsigned short)(u >> 16);
}

// dynamic-LDS byte offsets (s_conv region overlays s_emb region)
#define SE_PITCH 640                        // 320 bf16 per row, 66 rows
#define SC_PITCH 512                        // 256 bf16 per row, 64 rows (overlay)
#define SIM_OFF (66 * 640)                  // 42240
#define SIM_PITCH 66                        // floats per q-row
#define DYN_LDS (SIM_OFF + NQ * SIM_PITCH * 4)   // 50688 bytes

__device__ __forceinline__ float wave_reduce_sum(float v) {
#pragma unroll
    for (int off = 32; off; off >>= 1) v += __shfl_xor(v, off, 64);
    return v;
}

// top-5 pooling over 64 values for 8 q's simultaneously (8-lane groups).
__device__ __forceinline__ void top5_pool_g8(const float* v, int lane,
                                             float& mx, float& mn) {
    const float NEG = -3.4e38f;
    float s0 = NEG, s1 = NEG, s2 = NEG, s3 = NEG, s4 = NEG;
#pragma unroll
    for (int e = 0; e < 8; ++e) {
        float x = v[e], t;
        t = fmaxf(s0, x); x = fminf(s0, x); s0 = t;
        t = fmaxf(s1, x); x = fminf(s1, x); s1 = t;
        t = fmaxf(s2, x); x = fminf(s2, x); s2 = t;
        t = fmaxf(s3, x); x = fminf(s3, x); s3 = t;
        t = fmaxf(s4, x); x = fminf(s4, x); s4 = t;
    }
    int gb = lane & 56;
    int j = lane & 7;
    float sum = 0.f, first = 0.f;
#pragma unroll
    for (int i = 0; i < 5; ++i) {
        float m = s0;
        m = fmaxf(m, __shfl_xor(m, 1, 64));
        m = fmaxf(m, __shfl_xor(m, 2, 64));
        m = fmaxf(m, __shfl_xor(m, 4, 64));
        if (i == 0) first = m;
        sum += m;
        unsigned long long bal = __ballot(s0 == m);
        int leader = __ffsll((unsigned long long)((bal >> gb) & 0xffull)) - 1;
        if (j == leader) { s0 = s1; s1 = s2; s2 = s3; s3 = s4; s4 = NEG; }
    }
    mx = first;
    mn = sum * 0.2f;
}

// ---------- prep: blocks 0..119 pack conv_w -> Wb2 fragments (+zero qcssq/ctr);
//            blocks 120..263 gather q_emb (4 rows each) -> qe taps + qef fragments + q_norm
__global__ __launch_bounds__(256) void prep_kernel(
        const float* __restrict__ conv_w, const int* __restrict__ question,
        const float* __restrict__ embeds,
        short8* __restrict__ Wb2, unsigned short* __restrict__ qe,
        short8* __restrict__ qef, float* __restrict__ q_norm,
        float* __restrict__ qcssq, unsigned int* __restrict__ done_ctr) {
    int blk = blockIdx.x;
    int tid = threadIdx.x;
    if (blk < 120) {
        if (blk == 0 && tid == 0) done_ctr[0] = 0u;
        int i = blk * 256 + tid;
        if (i < NB * NQ) qcssq[i] = 0.f;
        int rl = i & 15;
        int ftile = (i >> 4) & 15;
        int c = i >> 8;
        int kg = c & 3, rest = c >> 2;
        int ks = rest % 10, j = rest / 10;
        int f = ftile * 16 + rl;
        int k0 = ks * 32 + kg * 8;
        const float* src = conv_w + (size_t)(f * 3 + j) * NE;
        short8 h;
#pragma unroll
        for (int e = 0; e < 8; ++e) {
            int k = k0 + e;
            h[e] = (short)((k < NE) ? f2bf(src[k]) : (unsigned short)0);
        }
        Wb2[i] = h;
    } else {
        int row = (blk - 120) * 4 + (tid >> 6);  // 0..575 = b*36 + r
        int b = row / QROWS, r = row % QROWS;
        int l = tid & 63;
        unsigned short* dst = qe + (size_t)row * KP;
        if (r < NQ) {
            int tok = question[b * NQ + r];
            const float4* rp = (const float4*)(embeds + (size_t)tok * NE);
            short8 h = {0, 0, 0, 0, 0, 0, 0, 0};
            float ss = 0.f;
            if (l < 38) {
                float4 v0 = rp[2 * l];
                ss += v0.x * v0.x + v0.y * v0.y + v0.z * v0.z + v0.w * v0.w;
                h[0] = (short)f2bf(v0.x); h[1] = (short)f2bf(v0.y);
                h[2] = (short)f2bf(v0.z); h[3] = (short)f2bf(v0.w);
                if (2 * l + 1 < 75) {
                    float4 v1 = rp[2 * l + 1];
                    ss += v1.x * v1.x + v1.y * v1.y + v1.z * v1.z + v1.w * v1.w;
                    h[4] = (short)f2bf(v1.x); h[5] = (short)f2bf(v1.y);
                    h[6] = (short)f2bf(v1.z); h[7] = (short)f2bf(v1.w);
                }
            }
            if (l < 40) {
                *(short8*)(dst + 8 * l) = h;
                qef[((size_t)(b * 2 + (r >> 4)) * 40 + l) * 16 + (r & 15)] = h;
            }
            ss = wave_reduce_sum(ss);
            if (l == 0) q_norm[b * NQ + r] = sqrtf(ss);
        } else {
            if (l < 40) {
                short8 z = {0, 0, 0, 0, 0, 0, 0, 0};
                *(short8*)(dst + 8 * l) = z;
            }
        }
    }
}

// ---------- q_conv via MFMA -> A-fragments + partial qc ssq (certified r9)
__global__ __launch_bounds__(256) void qconv_mfma_kernel(
        const unsigned short* __restrict__ qe, const short8* __restrict__ Wb2,
        short8* __restrict__ qcf, float* __restrict__ qcssq) {
    __shared__ unsigned short tile[NQ][72];
    int b = blockIdx.x >> 2, fq = blockIdx.x & 3;
    int tid = threadIdx.x, lane = tid & 63, w = tid >> 6;
    int rl = lane & 15, kg = lane >> 4;
    int ftile = fq * 4 + w;
    f32x4 acc0 = (f32x4){0.f, 0.f, 0.f, 0.f};
    f32x4 acc1 = (f32x4){0.f, 0.f, 0.f, 0.f};
    for (int j = 0; j < 3; ++j) {
#pragma unroll 2
        for (int ks = 0; ks < 10; ++ks) {
            int k = ks * 32 + kg * 8;
            int c = (j * 10 + ks) * 4 + kg;
            short8 a0 = *(const short8*)(qe + ((size_t)(b * QROWS) + rl + j) * KP + k);
            short8 a1 = *(const short8*)(qe + ((size_t)(b * QROWS) + 16 + rl + j) * KP + k);
            short8 bb = Wb2[(c * 16 + ftile) * 16 + rl];
            acc0 = MFMA(a0, bb, acc0);
            acc1 = MFMA(a1, bb, acc1);
        }
    }
    int fl = w * 16 + rl;
#pragma unroll
    for (int reg = 0; reg < 4; ++reg) {
        tile[kg * 4 + reg][fl] = f2bf(acc0[reg]);
        tile[16 + kg * 4 + reg][fl] = f2bf(acc1[reg]);
    }
    __syncthreads();
    {
        int mh = tid >> 7, c_local = (tid >> 4) & 7, rl2 = tid & 15;
        short8 h = *(const short8*)(&tile[mh * 16 + rl2][c_local * 8]);
        qcf[((size_t)(b * 2 + mh) * 32 + 8 * fq + c_local) * 16 + rl2] = h;
    }
    {
        int qq = tid >> 3, fgrp = tid & 7;
        short8 h = *(const short8*)(&tile[qq][fgrp * 8]);
        float ss = 0.f;
#pragma unroll
        for (int e = 0; e < 8; ++e) {
            float v = __uint_as_float(((unsigned)(unsigned short)h[e]) << 16);
            ss += v * v;
        }
        ss += __shfl_xor(ss, 1, 64);
        ss += __shfl_xor(ss, 2, 64);
        ss += __shfl_xor(ss, 4, 64);
        if (fgrp == 0) atomicAdd(&qcssq[b * NQ + qq], ss);
    }
}

// ---------- fused per-(b,s), 4 waves (r13 + parallel tail + gather ILP; barriers kept)
extern __shared__ char ldsc[];
__global__ __launch_bounds__(256, 3) void fused11_kernel(
    const int* __restrict__ sentences, const int* __restrict__ question,
    const float* __restrict__ sim_oh, const float* __restrict__ embeds,
    const short8* __restrict__ Wb2,
    const short8* __restrict__ qef, const short8* __restrict__ qcf,
    const float* __restrict__ q_norm, const float* __restrict__ qcssq,
    const float* __restrict__ lin_w, const float* __restrict__ lin_b,
    const int* __restrict__ tsent, const int* __restrict__ tdoc,
    unsigned int* __restrict__ done_ctr,
    float* __restrict__ sent_ws, float* __restrict__ d_out)
{
    __shared__ int toks[NL];
    __shared__ float smaskf[NL], snorm[NL], scnorm[NL];
    __shared__ float qn_s[NQ], qcn_s[NQ], qmf_s[NQ];
    __shared__ float wq[4];
    __shared__ int lastflag;
    __shared__ float red2[4];
    __shared__ float dred[NB];

    int tid = threadIdx.x, lane = tid & 63, w = tid >> 6;
    int rl = lane & 15, kg = lane >> 4;
    int bs = blockIdx.x, b = bs / NS;
    int t = (w << 4) + rl, t7 = t & 7;
    int pg = lane >> 3, pj = lane & 7;      // pooling group / chunk

    // ---- Phase 0: prefetch oh in group-of-8 layout (q = 8w+pg, t = 8pj..8pj+7)
    float ohv[8];
    {
        const float* ohp = sim_oh + ((size_t)bs * NQ + (w << 3) + pg) * NL + (pj << 3);
        float4 o0 = *(const float4*)(ohp);
        float4 o1 = *(const float4*)(ohp + 4);
        ohv[0] = o0.x; ohv[1] = o0.y; ohv[2] = o0.z; ohv[3] = o0.w;
        ohv[4] = o1.x; ohv[5] = o1.y; ohv[6] = o1.z; ohv[7] = o1.w;
    }

    // ---- header loads
    if (tid < NL) {
        int tk = sentences[(size_t)bs * NL + tid];
        toks[tid] = tk;
        smaskf[tid] = (tk > 1) ? 1.f : 0.f;
    } else if (tid < NL + NQ) {
        int q = tid - NL;
        qn_s[q] = q_norm[b * NQ + q];
    } else if (tid < NL + 2 * NQ) {
        int q = tid - NL - NQ;
        qcn_s[q] = sqrtf(qcssq[b * NQ + q]);
    } else if (tid < NL + 3 * NQ) {
        int q = tid - NL - 2 * NQ;
        qmf_s[q] = (question[b * NQ + q] > 1) ? 1.f : 0.f;
    }
    __syncthreads();

    // ---- Phase 1: gather s_emb -> LDS bf16 (swizzled). Hoist toks, unroll 8.
    if (w < 2) {                              // zero tail rows first
        int r = 64 + w;
        if (lane < 40) {
            uint4 z = {0, 0, 0, 0};
            *(uint4*)(ldsc + r * SE_PITCH + (lane << 4)) = z;
        }
    }
    {
        int tk[16];
#pragma unroll
        for (int i = 0; i < 16; ++i) tk[i] = toks[(i << 2) + w];
#pragma unroll 8
        for (int i = 0; i < 16; ++i) {
            int r = (i << 2) + w;
            char* rowbase = ldsc + r * SE_PITCH;
            int m7 = r & 7;
            const float4* rp = (const float4*)(embeds + (size_t)tk[i] * NE);
            {
                float4 v = rp[lane];
                ushort4 h = {f2bf(v.x), f2bf(v.y), f2bf(v.z), f2bf(v.w)};
                *(ushort4*)(rowbase + (((lane >> 1) ^ m7) << 4) + ((lane & 1) << 3)) = h;
            }
            if (lane < 11) {
                float4 v = rp[64 + lane];
                ushort4 h = {f2bf(v.x), f2bf(v.y), f2bf(v.z), f2bf(v.w)};
                int g = 64 + lane;
                *(ushort4*)(rowbase + (((g >> 1) ^ m7) << 4) + ((g & 1) << 3)) = h;
            }
            if (lane < 5) {
                int pk = 37 + ((lane + 1) >> 1);
                int sub = ((lane + 1) & 1) << 3;
                *(unsigned long long*)(rowbase + ((pk ^ m7) << 4) + sub) = 0ull;
            }
        }
    }
    __syncthreads();

    // ---- Phase 2: sim_ins MFMA (wave w = t-tile, M=32 q) + snorm via Gram diag
    {
        f32x4 iacc0 = (f32x4){0.f, 0.f, 0.f, 0.f};
        f32x4 iacc1 = (f32x4){0.f, 0.f, 0.f, 0.f};
        f32x4 nB = (f32x4){0.f, 0.f, 0.f, 0.f};
        const short8* qf = qef + (size_t)(b * 80) * 16;
#pragma unroll 2
        for (int ks = 0; ks < 10; ++ks) {
            int c = ks * 4 + kg;
            short8 bB = *(const short8*)(ldsc + t * SE_PITCH + ((c ^ t7) << 4));
            short8 a0 = qf[c * 16 + rl];
            short8 a1 = qf[(40 + c) * 16 + rl];
            iacc0 = MFMA(a0, bB, iacc0);
            iacc1 = MFMA(a1, bB, iacc1);
            nB = MFMA(bB, bB, nB);
        }
        if (kg == (rl >> 2)) snorm[t] = sqrtf(nB[rl & 3]);
        __syncthreads();

        // ---- Phase 3: scale + write sim_ins
        float inv_t = smaskf[t] / snorm[t];
#pragma unroll
        for (int reg = 0; reg < 4; ++reg) {
            int q0 = kg * 4 + reg;
            float s0 = iacc0[reg] / qn_s[q0] * inv_t * qmf_s[q0];
            *(float*)(ldsc + SIM_OFF + (q0 * SIM_PITCH + t) * 4) = s0;
            int q1 = 16 + kg * 4 + reg;
            float s1 = iacc1[reg] / qn_s[q1] * inv_t * qmf_s[q1];
            *(float*)(ldsc + SIM_OFF + (q1 * SIM_PITCH + t) * 4) = s1;
        }
    }
    __syncthreads();

    // ---- Phase 4: pool sim_ins (group-of-8, results live in registers)
    float f_i0, f_i1;
    {
        const float* basep = (const float*)(ldsc + SIM_OFF) +
                             ((w << 3) + pg) * SIM_PITCH + (pj << 3);
        float v[8];
#pragma unroll
        for (int e = 0; e < 8; e += 2) {
            float2 p = *(const float2*)(basep + e);
            v[e] = p.x; v[e + 1] = p.y;
        }
        top5_pool_g8(v, lane, f_i0, f_i1);
    }

    // ---- Phase 5: conv MFMA. wave w owns f-tiles 4w..4w+3, all 4 t-tiles.
    f32x4 cacc[4][4];
#pragma unroll
    for (int m = 0; m < 4; ++m)
#pragma unroll
        for (int nn = 0; nn < 4; ++nn) cacc[m][nn] = (f32x4){0.f, 0.f, 0.f, 0.f};
    for (int j = 0; j < 3; ++j) {
#pragma unroll 2
        for (int ks = 0; ks < 10; ++ks) {
            int c = (j * 10 + ks) * 4 + kg;
            short8 a[4], bb[4];
#pragma unroll
            for (int m = 0; m < 4; ++m) {
                int row = m * 16 + rl + j;
                a[m] = *(const short8*)(ldsc + row * SE_PITCH +
                                        ((((ks << 2) + kg) ^ (row & 7)) << 4));
            }
#pragma unroll
            for (int nn = 0; nn < 4; ++nn)
                bb[nn] = Wb2[(c * 16 + (w * 4 + nn)) * 16 + rl];
#pragma unroll
            for (int m = 0; m < 4; ++m)
#pragma unroll
                for (int nn = 0; nn < 4; ++nn)
                    cacc[m][nn] = MFMA(a[m], bb[nn], cacc[m][nn]);
        }
    }
    __syncthreads();   // all s_emb reads done; s_conv may overwrite

    // ---- Phase 6: write s_conv bf16 into (former s_emb) region
#pragma unroll
    for (int m = 0; m < 4; ++m)
#pragma unroll
        for (int nn = 0; nn < 4; ++nn) {
            int f = (w * 4 + nn) * 16 + rl;
#pragma unroll
            for (int reg = 0; reg < 4; ++reg) {
                int tr = m * 16 + kg * 4 + reg;
                *(unsigned short*)(ldsc + tr * SC_PITCH +
                                   (((f >> 3) ^ (tr & 7)) << 4) + ((f & 7) << 1)) =
                    f2bf(cacc[m][nn][reg]);
            }
        }
    __syncthreads();

    // ---- Phase 7: sim_sens MFMA (K=256) + scnorm via Gram diag
    {
        f32x4 sacc0 = (f32x4){0.f, 0.f, 0.f, 0.f};
        f32x4 sacc1 = (f32x4){0.f, 0.f, 0.f, 0.f};
        f32x4 nB = (f32x4){0.f, 0.f, 0.f, 0.f};
        const short8* qc = qcf + (size_t)(b * 64) * 16;
#pragma unroll 2
        for (int ks = 0; ks < 8; ++ks) {
            int c = ks * 4 + kg;
            short8 bB = *(const short8*)(ldsc + t * SC_PITCH + ((c ^ t7) << 4));
            short8 a0 = qc[c * 16 + rl];
            short8 a1 = qc[(32 + c) * 16 + rl];
            sacc0 = MFMA(a0, bB, sacc0);
            sacc1 = MFMA(a1, bB, sacc1);
            nB = MFMA(bB, bB, nB);
        }
        if (kg == (rl >> 2)) scnorm[t] = sqrtf(nB[rl & 3]);
        __syncthreads();

        // ---- Phase 8: scale + write sim_sens (reuse SIM buffer)
        float inv_t = 1.f / scnorm[t];
#pragma unroll
        for (int reg = 0; reg < 4; ++reg) {
            int q0 = kg * 4 + reg;
            *(float*)(ldsc + SIM_OFF + (q0 * SIM_PITCH + t) * 4) =
                sacc0[reg] / qcn_s[q0] * inv_t;
            int q1 = 16 + kg * 4 + reg;
            *(float*)(ldsc + SIM_OFF + (q1 * SIM_PITCH + t) * 4) =
                sacc1[reg] / qcn_s[q1] * inv_t;
        }
    }
    __syncthreads();

    // ---- Phase 9: pool sens + oh (group-of-8) + head
    {
        float lw0 = lin_w[0], lw1 = lin_w[1], lw2 = lin_w[2];
        float lw3 = lin_w[3], lw4 = lin_w[4], lw5 = lin_w[5];
        float lb = lin_b[0];
        const float* basep = (const float*)(ldsc + SIM_OFF) +
                             ((w << 3) + pg) * SIM_PITCH + (pj << 3);
        float sv[8];
#pragma unroll
        for (int e = 0; e < 8; e += 2) {
            float2 p = *(const float2*)(basep + e);
            sv[e] = p.x; sv[e + 1] = p.y;
        }
        float mxs, mns, mxo, mno;
        top5_pool_g8(sv, lane, mxs, mns);
        top5_pool_g8(ohv, lane, mxo, mno);
        float z = f_i0 * lw0 + f_i1 * lw1 + mxs * lw2 + mns * lw3 +
                  mxo * lw4 + mno * lw5 + lb;
        float p = 1.f / (1.f + expf(-z));
        float contrib = (pj == 0) ? p : 0.f;
        contrib += __shfl_xor(contrib, 8, 64);
        contrib += __shfl_xor(contrib, 16, 64);
        contrib += __shfl_xor(contrib, 32, 64);
        if (lane == 0) wq[w] = contrib;
    }
    __syncthreads();
    if (tid == 0) {
        float sent = (wq[0] + wq[1] + wq[2] + wq[3]) * (1.f / 32.f);
        __hip_atomic_store(&sent_ws[bs], sent, __ATOMIC_RELEASE, __HIP_MEMORY_SCOPE_AGENT);
        d_out[1 + bs] = sent;
        unsigned old = __hip_atomic_fetch_add(done_ctr, 1u, __ATOMIC_ACQ_REL,
                                              __HIP_MEMORY_SCOPE_AGENT);
        lastflag = (old == (unsigned)(NB * NS - 1)) ? 1 : 0;
    }
    __syncthreads();

    // ---- last block computes losses + doc_emit (fully parallel tail)
    if (lastflag) {
        float acc_l = 0.f;
#pragma unroll
        for (int k = 0; k < 3; ++k) {
            int i = tid + k * 256;
            float p = __hip_atomic_load(&sent_ws[i], __ATOMIC_ACQUIRE, __HIP_MEMORY_SCOPE_AGENT);
            float tt2 = (float)tsent[i];
            acc_l += tt2 * logf(p) + (1.f - tt2) * logf(1.f - p);
        }
        acc_l = wave_reduce_sum(acc_l);
        if ((tid & 63) == 0) red2[tid >> 6] = acc_l;

        {
            int bb2 = tid >> 4, j = tid & 15;
            float m = -3.4e38f;
#pragma unroll
            for (int k = 0; k < 3; ++k) {
                int s = j + k * 16;
                m = fmaxf(m, __hip_atomic_load(&sent_ws[bb2 * NS + s], __ATOMIC_ACQUIRE,
                                               __HIP_MEMORY_SCOPE_AGENT));
            }
            m = fmaxf(m, __shfl_xor(m, 1, 64));
            m = fmaxf(m, __shfl_xor(m, 2, 64));
            m = fmaxf(m, __shfl_xor(m, 4, 64));
            m = fmaxf(m, __shfl_xor(m, 8, 64));
            if (j == 0) {
                d_out[1 + NB * NS + bb2] = m;
                float tt2 = (float)tdoc[bb2];
                dred[bb2] = tt2 * logf(m) + (1.f - tt2) * logf(1.f - m);
            }
        }
        __syncthreads();
        if (tid == 0) {
            float sal = -(red2[0] + red2[1] + red2[2] + red2[3]) / (float)(NB * NS);
            float dsum = 0.f;
#pragma unroll
            for (int i = 0; i < NB; ++i) dsum += dred[i];
            float dal = -dsum / (float)NB;
            d_out[0] = 0.5f * (sal + dal);
        }
    }
}

extern "C" void kernel_launch(void* const* d_in, const int* in_sizes, int n_in,
                              void* d_out, int out_size, void* d_ws, size_t ws_size,
                              hipStream_t stream) {
    const int* sentences = (const int*)d_in[0];
    const int* question = (const int*)d_in[1];
    const int* tsent = (const int*)d_in[2];
    const int* tdoc = (const int*)d_in[3];
    const float* sim_oh = (const float*)d_in[4];
    const float* embeds = (const float*)d_in[5];
    const float* conv_w = (const float*)d_in[6];
    const float* lin_w = (const float*)d_in[7];
    const float* lin_b = (const float*)d_in[8];
    float* out = (float*)d_out;

    char* wsc = (char*)d_ws;
    short8* Wb2            = (short8*)(wsc);                     // 491520 B
    unsigned short* qe_old = (unsigned short*)(wsc + 491520);    // 368640 B
    short8* qef            = (short8*)(wsc + 860160);            // 327680 B
    short8* qcf            = (short8*)(wsc + 1187840);           // 262144 B
    float* q_norm          = (float*)(wsc + 1449984);            // 2048 B
    float* qcssq           = (float*)(wsc + 1452032);            // 2048 B
    float* sent_ws         = (float*)(wsc + 1454080);            // 3072 B
    unsigned int* done_ctr = (unsigned int*)(wsc + 1457152);     // 16 B

    hipFuncSetAttribute(reinterpret_cast<const void*>(fused11_kernel),
                        hipFuncAttributeMaxDynamicSharedMemorySize, DYN_LDS);

    prep_kernel<<<264, 256, 0, stream>>>(conv_w, question, embeds,
                                         Wb2, qe_old, qef, q_norm, qcssq, done_ctr);
    qconv_mfma_kernel<<<NB * 4, 256, 0, stream>>>(qe_old, Wb2, qcf, qcssq);
    fused11_kernel<<<NB * NS, 256, DYN_LDS, stream>>>(
        sentences, question, sim_oh, embeds, Wb2, qef, qcf, q_norm, qcssq,
        lin_w, lin_b, tsent, tdoc, done_ctr, sent_ws, out);
}